// Round 8
// baseline (699.641 us; speedup 1.0000x reference)
//
#include <hip/hip_runtime.h>
#include <math.h>

#define NN 50000
#define NE 50000
#define NNZ_E 800000
#define NBUCK 196   // buckets = seg >> 8, segs < 50176
#define BCAP 8192   // per-bucket capacity (avg fill 4082, 60+ sigma headroom)
#define EPB 2048    // edges per bin block

typedef _Float16 half_t;
typedef half_t half8 __attribute__((ext_vector_type(8)));
typedef half_t half4v __attribute__((ext_vector_type(4)));
typedef float floatx4 __attribute__((ext_vector_type(4)));
typedef float floatx8 __attribute__((ext_vector_type(8)));

// ---------------- CSR build: bucket binning ----------------

__global__ __launch_bounds__(256) void bin_kernel(const int* __restrict__ vi,
                                                  const int* __restrict__ hi,
                                                  int* __restrict__ bcur_e,
                                                  int* __restrict__ bcur_v,
                                                  unsigned int* __restrict__ tmp_e,
                                                  unsigned int* __restrict__ tmp_v) {
    __shared__ int cnt_e[NBUCK], cnt_v[NBUCK];
    __shared__ int gb_e[NBUCK], gb_v[NBUCK];
    int tid = threadIdx.x;
    for (int i = tid; i < NBUCK; i += 256) { cnt_e[i] = 0; cnt_v[i] = 0; }
    __syncthreads();
    int base = blockIdx.x * EPB;
    int nE = NNZ_E - base; if (nE > EPB) nE = EPB;
    int v[8], e[8], re[8], rv[8];
#pragma unroll
    for (int i = 0; i < 8; i++) {
        int off = i * 256 + tid;
        if (off < nE) {
            int k = base + off;
            v[i] = vi[k]; e[i] = hi[k];
            re[i] = atomicAdd(&cnt_e[e[i] >> 8], 1);
            rv[i] = atomicAdd(&cnt_v[v[i] >> 8], 1);
        }
    }
    __syncthreads();
    for (int i = tid; i < NBUCK; i += 256) {
        if (cnt_e[i] > 0) gb_e[i] = atomicAdd(&bcur_e[i], cnt_e[i]);
        if (cnt_v[i] > 0) gb_v[i] = atomicAdd(&bcur_v[i], cnt_v[i]);
    }
    __syncthreads();
#pragma unroll
    for (int i = 0; i < 8; i++) {
        int off = i * 256 + tid;
        if (off < nE) {
            int be = e[i] >> 8, bv = v[i] >> 8;
            tmp_e[(size_t)be * BCAP + gb_e[be] + re[i]] = ((unsigned)v[i] << 8) | (e[i] & 255);
            tmp_v[(size_t)bv * BCAP + gb_v[bv] + rv[i]] = ((unsigned)e[i] << 8) | (v[i] & 255);
        }
    }
}

__global__ __launch_bounds__(256) void fine_count(const int* __restrict__ bcur,
                                                  const unsigned int* __restrict__ tmp,
                                                  int* __restrict__ counts, int nseg) {
    __shared__ int h[256];
    int b = blockIdx.x, tid = threadIdx.x;
    h[tid] = 0;
    __syncthreads();
    int n = bcur[b];
    const unsigned int* t = tmp + (size_t)b * BCAP;
    for (int i = tid; i < n; i += 256) atomicAdd(&h[t[i] & 255], 1);
    __syncthreads();
    int seg = b * 256 + tid;
    if (seg < nseg) counts[seg] = h[tid];
}

__global__ __launch_bounds__(256) void fine_scatter(const int* __restrict__ bcur,
                                                    const unsigned int* __restrict__ tmp,
                                                    const int* __restrict__ offs,
                                                    int* __restrict__ payload, int nseg) {
    __shared__ int cur[256];
    int b = blockIdx.x, tid = threadIdx.x;
    int seg = b * 256 + tid;
    cur[tid] = (seg < nseg) ? offs[seg] : 0;
    __syncthreads();
    int n = bcur[b];
    const unsigned int* t = tmp + (size_t)b * BCAP;
    for (int i = tid; i < n; i += 256) {
        unsigned int r = t[i];
        int pos = atomicAdd(&cur[r & 255], 1);
        payload[pos] = r >> 8;
    }
}

// ---------------- scan (3-phase) ----------------

__global__ __launch_bounds__(256) void scan_blk(const int* __restrict__ counts,
                                                int* __restrict__ offs,
                                                int* __restrict__ blocksum, int n) {
    __shared__ int sh[256];
    int tid = threadIdx.x;
    int i = blockIdx.x * 256 + tid;
    int v = (i < n) ? counts[i] : 0;
    sh[tid] = v;
    __syncthreads();
    for (int o = 1; o < 256; o <<= 1) {
        int add = (tid >= o) ? sh[tid - o] : 0;
        __syncthreads();
        sh[tid] += add;
        __syncthreads();
    }
    if (i < n) offs[i] = sh[tid] - v;
    if (tid == 255) blocksum[blockIdx.x] = sh[255];
}

__global__ __launch_bounds__(256) void scan_top(const int* __restrict__ blocksum,
                                                int* __restrict__ blockbase, int nb) {
    __shared__ int sh[256];
    int tid = threadIdx.x;
    int v = (tid < nb) ? blocksum[tid] : 0;
    sh[tid] = v;
    __syncthreads();
    for (int o = 1; o < 256; o <<= 1) {
        int add = (tid >= o) ? sh[tid - o] : 0;
        __syncthreads();
        sh[tid] += add;
        __syncthreads();
    }
    if (tid < nb) blockbase[tid] = sh[tid] - v;
}

__global__ void scan_fix(const int* __restrict__ counts, const int* __restrict__ blockbase,
                         int* __restrict__ offs, float* __restrict__ inv, int n) {
    int i = blockIdx.x * 256 + threadIdx.x;
    if (i < n) {
        offs[i] = offs[i] + blockbase[i >> 8];
        inv[i] = 1.0f / fmaxf((float)counts[i], 1.0f);
    }
}

// ---------------- fp32 -> (hi,lo) fp16, chunk-major [ch>>5][row][32] -------

__global__ void cvt_split(const float* __restrict__ X, half_t* __restrict__ Xh,
                          half_t* __restrict__ Xl, int nrows) {
    int i = (blockIdx.x * 256 + threadIdx.x) * 4;
    if (i < nrows * 256) {
        float4 v = *(const float4*)(X + i);
        half4v h, l;
        h.x = (half_t)v.x; l.x = (half_t)(v.x - (float)h.x);
        h.y = (half_t)v.y; l.y = (half_t)(v.y - (float)h.y);
        h.z = (half_t)v.z; l.z = (half_t)(v.z - (float)h.z);
        h.w = (half_t)v.w; l.w = (half_t)(v.w - (float)h.w);
        int row = i >> 8, ch = i & 255;
        size_t di = (size_t)(ch >> 5) * nrows * 32 + (size_t)row * 32 + (ch & 31);
        *(half4v*)(Xh + di) = h;
        *(half4v*)(Xl + di) = l;
    }
}

__global__ void cvt_w(const float* __restrict__ W, half_t* __restrict__ Wth,
                      half_t* __restrict__ Wtl, int Kd, int Nd) {
    int idx = blockIdx.x * 256 + threadIdx.x;
    if (idx < Kd * Nd) {
        int k = idx / Nd, n = idx - k * Nd;
        float v = W[idx];
        half_t h = (half_t)v;
        Wth[(size_t)n * Kd + k] = h;
        Wtl[(size_t)n * Kd + k] = (half_t)(v - (float)h);
    }
}

// ---------------- split-fp16 MFMA GEMM ----------------
// A chunk-major [k>>5][M][32]; B [N][K] row-major; C chunk-major [n>>5][M][32].

#define LSTR 40

__global__ __launch_bounds__(256) void gemm_hsplit(const half_t* __restrict__ Ah,
                                                   const half_t* __restrict__ Al,
                                                   const half_t* __restrict__ Bh,
                                                   const half_t* __restrict__ Bl,
                                                   half_t* __restrict__ C,
                                                   int M, int N, int K) {
    __shared__ __attribute__((aligned(16))) half_t sAh[128 * LSTR];
    __shared__ __attribute__((aligned(16))) half_t sAl[128 * LSTR];
    __shared__ __attribute__((aligned(16))) half_t sBh[128 * LSTR];
    __shared__ __attribute__((aligned(16))) half_t sBl[128 * LSTR];

    int tid = threadIdx.x;
    int wave = tid >> 6, lane = tid & 63;
    int row0 = blockIdx.y * 128, col0 = blockIdx.x * 128;
    int qm = (wave >> 1) * 64, qn = (wave & 1) * 64;

    int sr = tid >> 1;
    int sk = (tid & 1) * 16;
    int fm = lane & 15;
    int fk = (lane >> 4) * 8;

    floatx4 acc[4][4] = {};

    for (int k0 = 0; k0 < K; k0 += 32) {
        half8 a0 = {}, a1 = {}, l0 = {}, l1 = {};
        int arow = row0 + sr;
        int kk = k0 + sk;  // 16-aligned, within one 32-chunk
        if (arow < M) {
            size_t ai = (size_t)(kk >> 5) * M * 32 + (size_t)arow * 32 + (kk & 31);
            a0 = *(const half8*)(Ah + ai); a1 = *(const half8*)(Ah + ai + 8);
            l0 = *(const half8*)(Al + ai); l1 = *(const half8*)(Al + ai + 8);
        }
        *(half8*)&sAh[sr * LSTR + sk]     = a0;
        *(half8*)&sAh[sr * LSTR + sk + 8] = a1;
        *(half8*)&sAl[sr * LSTR + sk]     = l0;
        *(half8*)&sAl[sr * LSTR + sk + 8] = l1;
        {
            const half_t* pb = Bh + (size_t)(col0 + sr) * K + k0 + sk;
            const half_t* pc = Bl + (size_t)(col0 + sr) * K + k0 + sk;
            half8 b0 = *(const half8*)pb, b1 = *(const half8*)(pb + 8);
            half8 c0 = *(const half8*)pc, c1 = *(const half8*)(pc + 8);
            *(half8*)&sBh[sr * LSTR + sk]     = b0;
            *(half8*)&sBh[sr * LSTR + sk + 8] = b1;
            *(half8*)&sBl[sr * LSTR + sk]     = c0;
            *(half8*)&sBl[sr * LSTR + sk + 8] = c1;
        }
        __syncthreads();

        half8 fa_h[4], fa_l[4], fb_h[4], fb_l[4];
#pragma unroll
        for (int i = 0; i < 4; i++) {
            fa_h[i] = *(const half8*)&sAh[(qm + i * 16 + fm) * LSTR + fk];
            fa_l[i] = *(const half8*)&sAl[(qm + i * 16 + fm) * LSTR + fk];
            fb_h[i] = *(const half8*)&sBh[(qn + i * 16 + fm) * LSTR + fk];
            fb_l[i] = *(const half8*)&sBl[(qn + i * 16 + fm) * LSTR + fk];
        }
#pragma unroll
        for (int mi = 0; mi < 4; mi++)
#pragma unroll
            for (int ni = 0; ni < 4; ni++) {
                acc[mi][ni] = __builtin_amdgcn_mfma_f32_16x16x32_f16(fa_h[mi], fb_h[ni], acc[mi][ni], 0, 0, 0);
                acc[mi][ni] = __builtin_amdgcn_mfma_f32_16x16x32_f16(fa_h[mi], fb_l[ni], acc[mi][ni], 0, 0, 0);
                acc[mi][ni] = __builtin_amdgcn_mfma_f32_16x16x32_f16(fa_l[mi], fb_h[ni], acc[mi][ni], 0, 0, 0);
            }
        __syncthreads();
    }

    int er = (lane >> 4) * 4;
    int ec = lane & 15;
#pragma unroll
    for (int mi = 0; mi < 4; mi++)
#pragma unroll
        for (int r = 0; r < 4; r++) {
            int grow = row0 + qm + mi * 16 + er + r;
            if (grow < M) {
#pragma unroll
                for (int ni = 0; ni < 4; ni++) {
                    int col = col0 + qn + ni * 16 + ec;
                    size_t ci = (size_t)(col >> 5) * M * 32 + (size_t)grow * 32 + (col & 31);
                    __builtin_nontemporal_store((half_t)acc[mi][ni][r], C + ci);
                }
            }
        }
}

// ---------------- chunk-sharded fp16 segment gather-reduce ------------------
// src chunk-major [NCHUNK][nsrc][32]; block's chunk = blockIdx.x % NCHUNK so all
// blocks for a chunk land on the same XCD (round-robin dispatch) -> per-XCD
// gather footprint = nsrc*64B = 3.2 MB, fits the 4 MB XCD L2.
// 4 lanes/row, 8 ch (16B) per lane. Payload via NT loads; dst via NT stores.
// MODE 0: dst_h = fp16(inv*sum); MODE 1: split(ELU(inv*sum+bias)); MODE 2: fp32.

template <int NCHUNK, int MODE>
__global__ __launch_bounds__(256) void seg16(const half_t* __restrict__ src,
                                             const int* __restrict__ offs,
                                             const int* __restrict__ counts,
                                             const int* __restrict__ payload,
                                             const float* __restrict__ inv,
                                             const float* __restrict__ bias,
                                             half_t* __restrict__ dst_h,
                                             half_t* __restrict__ dst_l,
                                             float* __restrict__ dst_f,
                                             int nrows, int nsrc) {
    int chunk = blockIdx.x % NCHUNK;
    int grp = blockIdx.x / NCHUNK;
    int tid = threadIdx.x;
    int row = grp * 64 + (tid >> 2);
    if (row >= nrows) return;
    int co = (tid & 3) * 8;  // offset within 32-ch chunk
    const half_t* sbase = src + (size_t)chunk * nsrc * 32 + co;
    int start = offs[row], cnt = counts[row];
    int j = start, end = start + cnt;
    floatx8 a0 = {}, a1 = {}, a2 = {}, a3 = {};
    for (; j + 4 <= end; j += 4) {
        int s0 = __builtin_nontemporal_load(payload + j);
        int s1 = __builtin_nontemporal_load(payload + j + 1);
        int s2 = __builtin_nontemporal_load(payload + j + 2);
        int s3 = __builtin_nontemporal_load(payload + j + 3);
        half8 v0 = *(const half8*)(sbase + (size_t)s0 * 32);
        half8 v1 = *(const half8*)(sbase + (size_t)s1 * 32);
        half8 v2 = *(const half8*)(sbase + (size_t)s2 * 32);
        half8 v3 = *(const half8*)(sbase + (size_t)s3 * 32);
        a0 += __builtin_convertvector(v0, floatx8);
        a1 += __builtin_convertvector(v1, floatx8);
        a2 += __builtin_convertvector(v2, floatx8);
        a3 += __builtin_convertvector(v3, floatx8);
    }
    for (; j < end; j++) {
        int sr = __builtin_nontemporal_load(payload + j);
        half8 v = *(const half8*)(sbase + (size_t)sr * 32);
        a0 += __builtin_convertvector(v, floatx8);
    }
    floatx8 acc = (a0 + a1) + (a2 + a3);
    acc *= inv[row];
    int gch = chunk * 32 + co;
    if (MODE >= 1) {
        float4 b0 = *(const float4*)(bias + gch);
        float4 b1 = *(const float4*)(bias + gch + 4);
        acc[0] += b0.x; acc[1] += b0.y; acc[2] += b0.z; acc[3] += b0.w;
        acc[4] += b1.x; acc[5] += b1.y; acc[6] += b1.z; acc[7] += b1.w;
    }
    if (MODE == 1) {
#pragma unroll
        for (int k = 0; k < 8; k++) acc[k] = acc[k] > 0.f ? acc[k] : expm1f(acc[k]);
        half8 h = __builtin_convertvector(acc, half8);
        floatx8 back = __builtin_convertvector(h, floatx8);
        half8 l = __builtin_convertvector(acc - back, half8);
        size_t di = (size_t)chunk * nrows * 32 + (size_t)row * 32 + co;
        __builtin_nontemporal_store(h, (half8*)(dst_h + di));
        __builtin_nontemporal_store(l, (half8*)(dst_l + di));
    } else if (MODE == 0) {
        size_t di = (size_t)chunk * nrows * 32 + (size_t)row * 32 + co;
        __builtin_nontemporal_store(__builtin_convertvector(acc, half8), (half8*)(dst_h + di));
    } else {
        float* o = dst_f + (size_t)row * (NCHUNK * 32) + gch;
        floatx4 lo = {acc[0], acc[1], acc[2], acc[3]};
        floatx4 hi4 = {acc[4], acc[5], acc[6], acc[7]};
        __builtin_nontemporal_store(lo, (floatx4*)o);
        __builtin_nontemporal_store(hi4, (floatx4*)(o + 4));
    }
}

// ---------------- launch ----------------

extern "C" void kernel_launch(void* const* d_in, const int* in_sizes, int n_in,
                              void* d_out, int out_size, void* d_ws, size_t ws_size,
                              hipStream_t stream) {
    const float* x  = (const float*)d_in[0];
    const int*   ei = (const int*)d_in[1];
    const int* vi = ei;
    const int* hi = ei + NNZ_E;
    const float* W1 = (const float*)d_in[3];
    const float* b1 = (const float*)d_in[4];
    const float* W2 = (const float*)d_in[5];
    const float* b2 = (const float*)d_in[6];
    const float* W3 = (const float*)d_in[7];
    const float* b3 = (const float*)d_in[8];
    float* out = (float*)d_out;

    char* p = (char*)d_ws;
    auto take = [&](size_t bytes) -> void* {
        void* r = (void*)p;
        p += (bytes + 255) & ~(size_t)255;
        return r;
    };
    const int NB = (NN + 255) / 256;
    int* counts_v = (int*)take(NN * 4);
    int* counts_e = (int*)take(NE * 4);
    int* offs_v   = (int*)take(NN * 4);
    int* offs_e   = (int*)take(NE * 4);
    int* bsum_v   = (int*)take(NB * 4);
    int* bsum_e   = (int*)take(NB * 4);
    int* bbase_v  = (int*)take(NB * 4);
    int* bbase_e  = (int*)take(NB * 4);
    int* bcur_e   = (int*)take(NBUCK * 4);
    int* bcur_v   = (int*)take(NBUCK * 4);
    unsigned int* tmp_e = (unsigned int*)take((size_t)NBUCK * BCAP * 4);
    unsigned int* tmp_v = (unsigned int*)take((size_t)NBUCK * BCAP * 4);
    int* pay_v    = (int*)take((size_t)NNZ_E * 4);
    int* pay_e    = (int*)take((size_t)NNZ_E * 4);
    float* inv_v  = (float*)take(NN * 4);
    float* inv_e  = (float*)take(NE * 4);
    half_t* msgH  = (half_t*)take((size_t)NN * 256 * 2);
    half_t* xeH   = (half_t*)take((size_t)NE * 256 * 2);
    half_t* hA_h  = (half_t*)take((size_t)NN * 256 * 2);
    half_t* hA_l  = (half_t*)take((size_t)NN * 256 * 2);
    half_t* w1h   = (half_t*)take(256 * 256 * 2);
    half_t* w1l   = (half_t*)take(256 * 256 * 2);
    half_t* w2h   = (half_t*)take(256 * 256 * 2);
    half_t* w2l   = (half_t*)take(256 * 256 * 2);
    half_t* w3h   = (half_t*)take(256 * 128 * 2);
    half_t* w3l   = (half_t*)take(256 * 128 * 2);

    // ---- CSR build ----
    hipMemsetAsync(bcur_e, 0, NBUCK * 4, stream);
    hipMemsetAsync(bcur_v, 0, NBUCK * 4, stream);
    bin_kernel<<<(NNZ_E + EPB - 1) / EPB, 256, 0, stream>>>(vi, hi, bcur_e, bcur_v, tmp_e, tmp_v);
    fine_count<<<NBUCK, 256, 0, stream>>>(bcur_e, tmp_e, counts_e, NE);
    fine_count<<<NBUCK, 256, 0, stream>>>(bcur_v, tmp_v, counts_v, NN);
    scan_blk<<<NB, 256, 0, stream>>>(counts_v, offs_v, bsum_v, NN);
    scan_blk<<<NB, 256, 0, stream>>>(counts_e, offs_e, bsum_e, NE);
    scan_top<<<1, 256, 0, stream>>>(bsum_v, bbase_v, NB);
    scan_top<<<1, 256, 0, stream>>>(bsum_e, bbase_e, NB);
    scan_fix<<<NB, 256, 0, stream>>>(counts_v, bbase_v, offs_v, inv_v, NN);
    scan_fix<<<NB, 256, 0, stream>>>(counts_e, bbase_e, offs_e, inv_e, NE);
    fine_scatter<<<NBUCK, 256, 0, stream>>>(bcur_e, tmp_e, offs_e, pay_e, NE);
    fine_scatter<<<NBUCK, 256, 0, stream>>>(bcur_v, tmp_v, offs_v, pay_v, NN);

    // ---- conversions ----
    cvt_split<<<(NN * 256 / 4 + 255) / 256, 256, 0, stream>>>(x, hA_h, hA_l, NN);
    cvt_w<<<(256 * 256 + 255) / 256, 256, 0, stream>>>(W1, w1h, w1l, 256, 256);
    cvt_w<<<(256 * 256 + 255) / 256, 256, 0, stream>>>(W2, w2h, w2l, 256, 256);
    cvt_w<<<(256 * 128 + 255) / 256, 256, 0, stream>>>(W3, w3h, w3l, 256, 128);

    dim3 g256(2, (NN + 127) / 128);
    dim3 g128(1, (NN + 127) / 128);
    int grpN = (NN + 63) / 64;
    int gridC256 = 8 * grpN;  // NCHUNK=8
    int gridC128 = 4 * grpN;  // NCHUNK=4

    // ---- layer 1 ----
    gemm_hsplit<<<g256, 256, 0, stream>>>(hA_h, hA_l, w1h, w1l, msgH, NN, 256, 256);
    seg16<8, 0><<<gridC256, 256, 0, stream>>>(msgH, offs_e, counts_e, pay_e, inv_e,
                                              nullptr, xeH, nullptr, nullptr, NE, NN);
    seg16<8, 1><<<gridC256, 256, 0, stream>>>(xeH, offs_v, counts_v, pay_v, inv_v,
                                              b1, hA_h, hA_l, nullptr, NN, NE);
    // ---- layer 2 ----
    gemm_hsplit<<<g256, 256, 0, stream>>>(hA_h, hA_l, w2h, w2l, msgH, NN, 256, 256);
    seg16<8, 0><<<gridC256, 256, 0, stream>>>(msgH, offs_e, counts_e, pay_e, inv_e,
                                              nullptr, xeH, nullptr, nullptr, NE, NN);
    seg16<8, 1><<<gridC256, 256, 0, stream>>>(xeH, offs_v, counts_v, pay_v, inv_v,
                                              b2, hA_h, hA_l, nullptr, NN, NE);
    // ---- layer 3 (C=128, no activation) ----
    gemm_hsplit<<<g128, 256, 0, stream>>>(hA_h, hA_l, w3h, w3l, msgH, NN, 128, 256);
    seg16<4, 0><<<gridC128, 256, 0, stream>>>(msgH, offs_e, counts_e, pay_e, inv_e,
                                              nullptr, xeH, nullptr, nullptr, NE, NN);
    seg16<4, 2><<<gridC128, 256, 0, stream>>>(xeH, offs_v, counts_v, pay_v, inv_v,
                                              b3, nullptr, nullptr, out, NN, NE);
}